// Round 10
// baseline (2014.435 us; speedup 1.0000x reference)
//
#include <hip/hip_runtime.h>
#include <stdint.h>

#define FP8_MAX 448.0f
#define BSQ 128          // quantization block size
#define BM 256
#define BN 256
#define BK 64            // K-tile
#define NT 64            // K / BK
#define NKB 32           // K / BSQ

typedef int   i32x4  __attribute__((ext_vector_type(4)));
typedef int   i32x8  __attribute__((ext_vector_type(8)));
typedef float f32x4v __attribute__((ext_vector_type(4)));
typedef float f32x16 __attribute__((ext_vector_type(16)));

typedef const __attribute__((address_space(1))) uint8_t* gptr_t;
typedef __attribute__((address_space(3))) uint8_t* lptr_t;

// ---------------- activation quantization: per (row, 128-block) ----------------
__global__ void act_quant_kernel(const float* __restrict__ x,
                                 uint8_t* __restrict__ xq,
                                 float* __restrict__ sxT,
                                 int M, int K) {
    int gid  = blockIdx.x * blockDim.x + threadIdx.x;
    int wave = gid >> 6;
    int lane = threadIdx.x & 63;
    int nkb  = K / BSQ;
    int row  = wave / nkb;
    int kb   = wave - row * nkb;
    if (row >= M) return;

    const float2 v = *(const float2*)(x + (size_t)row * K + kb * BSQ + lane * 2);
    float am = fmaxf(fabsf(v.x), fabsf(v.y));
#pragma unroll
    for (int off = 32; off >= 1; off >>= 1)
        am = fmaxf(am, __shfl_xor(am, off));

    float s = am / FP8_MAX;                    // matches reference: amax/448 in fp32
    if (lane == 0) sxT[(size_t)kb * M + row] = s;

    float q0 = (am > 0.f) ? v.x / s : 0.f;     // fp32 IEEE division, then RNE->e4m3
    float q1 = (am > 0.f) ? v.y / s : 0.f;
    int packed = __builtin_amdgcn_cvt_pk_fp8_f32(q0, q1, 0, false);
    *(uint16_t*)(xq + (size_t)row * K + kb * BSQ + lane * 2) = (uint16_t)(packed & 0xffff);
}

// ---------------- weight cast fp32(fp8-representable) -> e4m3 bytes ----------------
__global__ void weight_quant_kernel(const float* __restrict__ w,
                                    uint8_t* __restrict__ wq, size_t n) {
    size_t i = ((size_t)blockIdx.x * blockDim.x + threadIdx.x) * 4;
    if (i >= n) return;
    float4 v = *(const float4*)(w + i);
    int lo = __builtin_amdgcn_cvt_pk_fp8_f32(v.x, v.y, 0, false);
    int hi = __builtin_amdgcn_cvt_pk_fp8_f32(v.z, v.w, 0, false);
    *(uint32_t*)(wq + i) = (uint32_t)((lo & 0xffff) | (hi << 16));
}

// ---------------- 256^2 8-phase MX GEMM, BK=64, 3-deep counted pipeline ----------------
// Swizzle (BK=64 rows = 64B): involution byte ^= ((byte>>7)&7)<<4 within each
// 16KB tile; 8 consecutive lanes of a 32-row fragment read -> 8 distinct bank
// groups (conflict-free, same property as the verified BK=128 hsw layout).
// Ledger: stream(kt) = [scale? , A_h0, A_h1, B_h0, B_h1] = 5 if kt even else 4,
// issued one piece per phase while computing kt-2. One vmcnt per K-tile at
// phase 3: allowed = |stream(kt+2)| (never 0 until the 2-tile tail).
__global__ __launch_bounds__(512, 2)
void fp8_gemm_mx8p(const uint8_t* __restrict__ Aq,   // [M][K] e4m3
                   const uint8_t* __restrict__ Bq,   // [N][K] e4m3
                   const float*  __restrict__ sxT,   // [K/128][M]
                   const float*  __restrict__ swg,   // [N/128][K/128]
                   float* __restrict__ out,          // [M][N]
                   int M, int N, int K) {
    __shared__ uint8_t As[3][BM * BK];   // 3 x 16 KB
    __shared__ uint8_t Bs[3][BN * BK];   // 3 x 16 KB
    __shared__ float   sxs[2][BM];       // 2 x 1 KB
    __shared__ float   swl[2 * NKB];     // weight scales for both n-panels

    const int tid  = threadIdx.x;
    const int lane = tid & 63;
    const int wid  = tid >> 6;           // 0..7
    const int wy   = wid >> 2;           // 0..1 (128 rows)
    const int wx   = wid & 3;            // 0..3 (64 cols)
    const int fl   = lane & 31;
    const int hi   = lane >> 5;

    // XCD-aware chunked swizzle; nwg = 1024 (divisible by 8)
    const int bid  = blockIdx.x;
    const int swz  = (bid & 7) * (gridDim.x >> 3) + (bid >> 3);
    const int nbx  = N / BN;
    const int brow = (swz / nbx) * BM;
    const int bcol = (swz % nbx) * BN;

    auto STAGE_A = [&](int buf, int kt, int h) {
        int ph   = (h * 512 + tid) * 16;           // phys byte in 16KB tile
        int lb   = ph ^ (((ph >> 7) & 7) << 4);    // involution -> logical byte
        int lrow = lb >> 6;
        int lg   = (lb >> 4) & 3;
        const uint8_t* g = Aq + (size_t)(brow + lrow) * K + kt * BK + lg * 16;
        __builtin_amdgcn_global_load_lds((gptr_t)g,
            (lptr_t)(As[buf] + h * 8192 + (tid & ~63) * 16), 16, 0, 0);
    };
    auto STAGE_B = [&](int buf, int kt, int h) {
        int ph   = (h * 512 + tid) * 16;
        int lb   = ph ^ (((ph >> 7) & 7) << 4);
        int lrow = lb >> 6;
        int lg   = (lb >> 4) & 3;
        const uint8_t* g = Bq + (size_t)(bcol + lrow) * K + kt * BK + lg * 16;
        __builtin_amdgcn_global_load_lds((gptr_t)g,
            (lptr_t)(Bs[buf] + h * 8192 + (tid & ~63) * 16), 16, 0, 0);
    };
    auto STAGE_S = [&](int buf, int kb) {  // every wave issues exactly 1 op
        const float* gs = sxT + (size_t)kb * M + brow + wid * 32 + (lane & 31);
        if (lane < 32)
            __builtin_amdgcn_global_load_lds((gptr_t)(const uint8_t*)gs,
                (lptr_t)(sxs[buf] + wid * 32), 4, 0, 0);
    };

    const f32x16 zz = {0.f,0.f,0.f,0.f, 0.f,0.f,0.f,0.f,
                       0.f,0.f,0.f,0.f, 0.f,0.f,0.f,0.f};
    f32x16 acc[4][2];
#pragma unroll
    for (int i = 0; i < 4; ++i)
#pragma unroll
        for (int j = 0; j < 2; ++j) acc[i][j] = zz;

    // prologue: sw row (64 floats, one inst/wave), then streams kt=0, kt=1
    {
        const float* g = swg + (size_t)(bcol >> 7) * NKB + lane;
        __builtin_amdgcn_global_load_lds((gptr_t)(const uint8_t*)g,
            (lptr_t)swl, 4, 0, 0);
    }
    STAGE_S(0, 0);
    STAGE_A(0, 0, 0); STAGE_A(0, 0, 1); STAGE_B(0, 0, 0); STAGE_B(0, 0, 1);
    STAGE_A(1, 1, 0); STAGE_A(1, 1, 1); STAGE_B(1, 1, 0); STAGE_B(1, 1, 1);
    asm volatile("s_waitcnt vmcnt(4)" ::: "memory");   // sw,s0,tile0 resident
    __builtin_amdgcn_s_barrier();
    asm volatile("" ::: "memory");

    int cur = 0;
    for (int kt = 0; kt < NT; ++kt) {
        const int kb  = kt >> 1;
        const int nxt = (cur == 0) ? 2 : cur - 1;     // (cur+2)%3
        const bool pf = (kt + 2 < NT);
        const uint8_t* Ab = As[cur];
        const uint8_t* Bb = Bs[cur];
        const float*   Sb = sxs[kb & 1];
        const float    sw = swl[(wx >> 1) * NKB + kb];  // LDS broadcast read

        i32x8 bfr[2];
#pragma unroll
        for (int fm = 0; fm < 4; ++fm) {
            // ---- ds_reads for this phase ----
            if (fm == 0) {
#pragma unroll
                for (int fn = 0; fn < 2; ++fn) {
                    int r = wx * 64 + fn * 32 + fl;
                    int a0 = (r * 64 + (hi * 2) * 16)     ^ (((r >> 1) & 7) << 4);
                    int a1 = (r * 64 + (hi * 2 + 1) * 16) ^ (((r >> 1) & 7) << 4);
                    i32x4 lo = *(const i32x4*)(Bb + a0);
                    i32x4 h4 = *(const i32x4*)(Bb + a1);
                    bfr[fn] = (i32x8){lo.x, lo.y, lo.z, lo.w, h4.x, h4.y, h4.z, h4.w};
                }
            }
            i32x8 afr;
            {
                int r = wy * 128 + fm * 32 + fl;
                int a0 = (r * 64 + (hi * 2) * 16)     ^ (((r >> 1) & 7) << 4);
                int a1 = (r * 64 + (hi * 2 + 1) * 16) ^ (((r >> 1) & 7) << 4);
                i32x4 lo = *(const i32x4*)(Ab + a0);
                i32x4 h4 = *(const i32x4*)(Ab + a1);
                afr = (i32x8){lo.x, lo.y, lo.z, lo.w, h4.x, h4.y, h4.z, h4.w};
            }
            f32x4v s4[4];
#pragma unroll
            for (int q = 0; q < 4; ++q) {
                s4[q] = *(const f32x4v*)&Sb[wy * 128 + fm * 32 + q * 8 + hi * 4];
                s4[q] *= sw;
            }

            // ---- stage one piece of stream(kt+2) ----
            if (pf) {
                if (fm == 0) {
                    if ((kt & 1) == 0) STAGE_S((kb + 1) & 1, kb + 1);
                    STAGE_A(nxt, kt + 2, 0);
                } else if (fm == 1) STAGE_A(nxt, kt + 2, 1);
                else if (fm == 2)   STAGE_B(nxt, kt + 2, 0);
                else                STAGE_B(nxt, kt + 2, 1);
            }

            // ---- counted wait once per K-tile (phase 3), then barrier ----
            if (fm == 3) {
                if (pf) {
                    if (kt & 1) asm volatile("s_waitcnt vmcnt(4)" ::: "memory");
                    else        asm volatile("s_waitcnt vmcnt(5)" ::: "memory");
                } else if (kt + 1 < NT) {
                    asm volatile("s_waitcnt vmcnt(0)" ::: "memory");
                }
            }
            __builtin_amdgcn_s_barrier();
            asm volatile("s_waitcnt lgkmcnt(0)" ::: "memory");
            __builtin_amdgcn_sched_barrier(0);

            __builtin_amdgcn_s_setprio(1);
            f32x16 p0 = __builtin_amdgcn_mfma_scale_f32_32x32x64_f8f6f4(
                afr, bfr[0], zz, 0, 0, 0, 127, 0, 127);
            f32x16 p1 = __builtin_amdgcn_mfma_scale_f32_32x32x64_f8f6f4(
                afr, bfr[1], zz, 0, 0, 0, 127, 0, 127);
            __builtin_amdgcn_s_setprio(0);

#pragma unroll
            for (int q = 0; q < 4; ++q)
#pragma unroll
                for (int j = 0; j < 4; ++j) {
                    acc[fm][0][q * 4 + j] += p0[q * 4 + j] * s4[q][j];
                    acc[fm][1][q * 4 + j] += p1[q * 4 + j] * s4[q][j];
                }
            __builtin_amdgcn_s_barrier();
            asm volatile("" ::: "memory");
        }
        cur = (cur == 2) ? 0 : cur + 1;
    }

    // epilogue: C/D 32x32 layout col=lane&31, row=(reg&3)+8*(reg>>2)+4*(lane>>5)
#pragma unroll
    for (int fm = 0; fm < 4; ++fm)
#pragma unroll
        for (int fn = 0; fn < 2; ++fn)
#pragma unroll
            for (int q = 0; q < 4; ++q)
#pragma unroll
                for (int j = 0; j < 4; ++j) {
                    int row = brow + wy * 128 + fm * 32 + q * 8 + hi * 4 + j;
                    int col = bcol + wx * 64 + fn * 32 + fl;
                    __builtin_nontemporal_store(acc[fm][fn][q * 4 + j],
                                                &out[(size_t)row * N + col]);
                }
}

extern "C" void kernel_launch(void* const* d_in, const int* in_sizes, int n_in,
                              void* d_out, int out_size, void* d_ws, size_t ws_size,
                              hipStream_t stream) {
    const float* x   = (const float*)d_in[0];
    const float* w   = (const float*)d_in[1];
    const float* wsi = (const float*)d_in[2];
    float* out = (float*)d_out;

    const int K = 4096;
    const int M = in_sizes[0] / K;       // 4096
    const int N = in_sizes[1] / K;       // 16384

    uint8_t* xq  = (uint8_t*)d_ws;                      // M*K bytes
    uint8_t* wq  = xq + (size_t)M * K;                  // N*K bytes
    float*   sxT = (float*)(wq + (size_t)N * K);        // (K/128)*M floats

    int waves = M * (K / BSQ);
    act_quant_kernel<<<dim3(waves / 4), dim3(256), 0, stream>>>(x, xq, sxT, M, K);

    size_t wn = (size_t)N * K;
    weight_quant_kernel<<<dim3((unsigned)(wn / 4 / 256)), dim3(256), 0, stream>>>(w, wq, wn);

    dim3 grid((N / BN) * (M / BM));      // 1024, 1D for swizzle
    fp8_gemm_mx8p<<<grid, dim3(512), 0, stream>>>(xq, wq, sxT, wsi, out, M, N, K);
}

// Round 11
// 461.213 us; speedup vs baseline: 4.3677x; 4.3677x over previous
//
#include <hip/hip_runtime.h>
#include <stdint.h>

#define FP8_MAX 448.0f
#define BSQ 128          // quantization block size
#define TM 128
#define TN 128
#define NKB 32           // K / BSQ

typedef int   i32x4  __attribute__((ext_vector_type(4)));
typedef int   i32x8  __attribute__((ext_vector_type(8)));
typedef float f32x4v __attribute__((ext_vector_type(4)));
typedef float f32x16 __attribute__((ext_vector_type(16)));

typedef const __attribute__((address_space(1))) uint8_t* gptr_t;
typedef __attribute__((address_space(3))) uint8_t* lptr_t;

// 3-bit granule hash: 32-row fragment b128 reads spread evenly over all
// 8 granule-columns -> bank-minimal (verified: 0 conflicts rounds 3-9).
__device__ __forceinline__ int hsw(int row) { return (row ^ (row >> 3)) & 7; }

// ---------------- activation quantization: per (row, 128-block) ----------------
// scales written TRANSPOSED: sxT[kb*M + row]  (lane-linear gather in GEMM stage)
__global__ void act_quant_kernel(const float* __restrict__ x,
                                 uint8_t* __restrict__ xq,
                                 float* __restrict__ sxT,
                                 int M, int K) {
    int gid  = blockIdx.x * blockDim.x + threadIdx.x;
    int wave = gid >> 6;
    int lane = threadIdx.x & 63;
    int nkb  = K / BSQ;
    int row  = wave / nkb;
    int kb   = wave - row * nkb;
    if (row >= M) return;

    const float2 v = *(const float2*)(x + (size_t)row * K + kb * BSQ + lane * 2);
    float am = fmaxf(fabsf(v.x), fabsf(v.y));
#pragma unroll
    for (int off = 32; off >= 1; off >>= 1)
        am = fmaxf(am, __shfl_xor(am, off));

    float s = am / FP8_MAX;                    // matches reference: amax/448 in fp32
    if (lane == 0) sxT[(size_t)kb * M + row] = s;

    float q0 = (am > 0.f) ? v.x / s : 0.f;     // fp32 IEEE division, then RNE->e4m3
    float q1 = (am > 0.f) ? v.y / s : 0.f;
    int packed = __builtin_amdgcn_cvt_pk_fp8_f32(q0, q1, 0, false);
    *(uint16_t*)(xq + (size_t)row * K + kb * BSQ + lane * 2) = (uint16_t)(packed & 0xffff);
}

// ---------------- weight cast fp32(fp8-representable) -> e4m3 bytes ----------------
__global__ void weight_quant_kernel(const float* __restrict__ w,
                                    uint8_t* __restrict__ wq, size_t n) {
    size_t i = ((size_t)blockIdx.x * blockDim.x + threadIdx.x) * 4;
    if (i >= n) return;
    float4 v = *(const float4*)(w + i);
    int lo = __builtin_amdgcn_cvt_pk_fp8_f32(v.x, v.y, 0, false);
    int hi = __builtin_amdgcn_cvt_pk_fp8_f32(v.z, v.w, 0, false);
    *(uint32_t*)(wq + i) = (uint32_t)((lo & 0xffff) | (hi << 16));
}

// ---------------- 128^2 dbuf MX GEMM (R5 champion) + hoisted staging addresses ----------------
// y[m,n] = sum_kb sx[m,kb]*sw[nb,kb] * dot_fp8(x[m,kb*128:+128], w[n,kb*128:+128])
// Staging pointers are loop-invariant up to +kb*BSQ (A/B) and +kb*M*4 (scales):
// precomputed once, offset by a uniform scalar per step (strength reduction).
__global__ __launch_bounds__(256, 2)
void fp8_gemm_mx(const uint8_t* __restrict__ Aq,   // [M][K] e4m3
                 const uint8_t* __restrict__ Bq,   // [N][K] e4m3
                 const float*  __restrict__ sxT,   // [K/128][M]  (transposed)
                 const float*  __restrict__ swg,   // [N/128][K/128]
                 float* __restrict__ out,          // [M][N]
                 int M, int N, int K) {
    __shared__ uint8_t As[2][TM * BSQ];      // 2 x 16 KB, granule-swizzled rows
    __shared__ uint8_t Bs[2][TN * BSQ];      // 2 x 16 KB
    __shared__ float   sxs[2][TM];           // 2 x 0.5 KB raw sx row

    const int tid  = threadIdx.x;
    const int lane = tid & 63;
    const int wid  = tid >> 6;
    const int brow = blockIdx.y * TM;
    const int bcol = blockIdx.x * TN;
    const int nb   = bcol >> 7;

    const int wy = wid >> 1, wx = wid & 1;   // 2x2 wave grid, 64x64 per wave
    const int fl = lane & 31, hi = lane >> 5;

    // ---- hoisted staging addresses (kb=0); step offset is uniform kb*BSQ ----
    const uint8_t* gApt[4];
    const uint8_t* gBpt[4];
#pragma unroll
    for (int r = 0; r < 4; ++r) {
        int slot = r * 256 + tid;            // 0..1023 16B-slots
        int row  = slot >> 3;                // 0..127
        int g    = (slot & 7) ^ hsw(row);    // pre-swizzled source granule
        gApt[r] = Aq + (size_t)(brow + row) * K + g * 16;
        gBpt[r] = Bq + (size_t)(bcol + row) * K + g * 16;
    }
    const uint8_t* gSpt = (const uint8_t*)(sxT + brow + wid * 64 + lane);

    // staging: LDS dest linear (wave-uniform base + lane*16), src pre-swizzled
    auto STAGE = [&](int buf, int kb) {
        const size_t ko = (size_t)kb * BSQ;
        const size_t so = (size_t)kb * M * 4;
#pragma unroll
        for (int r = 0; r < 4; ++r) {
            int slot = r * 256 + tid;
            __builtin_amdgcn_global_load_lds((gptr_t)(gApt[r] + ko),
                (lptr_t)(As[buf] + (slot & ~63) * 16), 16, 0, 0);
            __builtin_amdgcn_global_load_lds((gptr_t)(gBpt[r] + ko),
                (lptr_t)(Bs[buf] + (slot & ~63) * 16), 16, 0, 0);
        }
        if (wid < 2) {                       // 128-float scale row, lane x 4B linear
            __builtin_amdgcn_global_load_lds((gptr_t)(gSpt + so),
                (lptr_t)(sxs[buf] + wid * 64), 4, 0, 0);
        }
    };

    const f32x16 zz = {0.f,0.f,0.f,0.f, 0.f,0.f,0.f,0.f,
                       0.f,0.f,0.f,0.f, 0.f,0.f,0.f,0.f};
    f32x16 acc[2][2];
#pragma unroll
    for (int i = 0; i < 2; ++i)
#pragma unroll
        for (int j = 0; j < 2; ++j) acc[i][j] = zz;

    // prologue: stage kb=0, drain once (__syncthreads inserts vmcnt(0))
    STAGE(0, 0);
    __syncthreads();

    for (int kb = 0; kb < NKB; ++kb) {
        const int cur = kb & 1;
        const uint8_t* Ab = As[cur];
        const uint8_t* Bb = Bs[cur];
        const float*   Sb = sxs[cur];

        // issue next tile's loads FIRST: latency hides under this step's compute
        if (kb + 1 < NKB) STAGE(cur ^ 1, kb + 1);

        const float sw = swg[(size_t)nb * NKB + kb];   // block-uniform weight scale

        // B fragments (8 x b128), reused across fm
        i32x8 bfr[2][2];
#pragma unroll
        for (int fn = 0; fn < 2; ++fn) {
            int row = wx * 64 + fn * 32 + fl;
            int hh  = hsw(row);
            const uint8_t* base = Bb + row * BSQ;
#pragma unroll
            for (int kh = 0; kh < 2; ++kh) {
                int g0 = kh * 4 + hi * 2;
                i32x4 lo = *(const i32x4*)(base + (((g0    ) ^ hh) << 4));
                i32x4 h4 = *(const i32x4*)(base + (((g0 + 1) ^ hh) << 4));
                bfr[fn][kh] = (i32x8){lo.x, lo.y, lo.z, lo.w, h4.x, h4.y, h4.z, h4.w};
            }
        }

#pragma unroll
        for (int fm = 0; fm < 2; ++fm) {
            int arow = wy * 64 + fm * 32 + fl;
            int hh   = hsw(arow);
            const uint8_t* abase = Ab + arow * BSQ;
            i32x8 afr[2];
#pragma unroll
            for (int kh = 0; kh < 2; ++kh) {
                int g0 = kh * 4 + hi * 2;
                i32x4 lo = *(const i32x4*)(abase + (((g0    ) ^ hh) << 4));
                i32x4 h4 = *(const i32x4*)(abase + (((g0 + 1) ^ hh) << 4));
                afr[kh] = (i32x8){lo.x, lo.y, lo.z, lo.w, h4.x, h4.y, h4.z, h4.w};
            }
            // per-row scales (broadcast b128 reads) x block-uniform sw
            f32x4v s4[4];
#pragma unroll
            for (int q = 0; q < 4; ++q) {
                s4[q] = *(const f32x4v*)&Sb[wy * 64 + fm * 32 + q * 8 + hi * 4];
                s4[q] *= sw;
            }

#pragma unroll
            for (int fn = 0; fn < 2; ++fn) {
                // unit HW scales (e8m0 127 -> x1.0); exact fp32 fold below
                f32x16 p = __builtin_amdgcn_mfma_scale_f32_32x32x64_f8f6f4(
                    afr[0], bfr[fn][0], zz, 0, 0, 0, 127, 0, 127);
                p = __builtin_amdgcn_mfma_scale_f32_32x32x64_f8f6f4(
                    afr[1], bfr[fn][1], p, 0, 0, 0, 127, 0, 127);
#pragma unroll
                for (int q = 0; q < 4; ++q)
#pragma unroll
                    for (int j = 0; j < 4; ++j)
                        acc[fm][fn][q * 4 + j] += p[q * 4 + j] * s4[q][j];
            }
        }

        // single drain point per step: next tile resident before buffer swap.
        // At 2 blocks/CU the co-resident block computes through this wait.
        __syncthreads();
    }

    // epilogue: C/D 32x32 layout col=lane&31, row=(reg&3)+8*(reg>>2)+4*(lane>>5)
    // nontemporal: 268MB streaming writes must not evict L3-resident fp8 panels
#pragma unroll
    for (int fm = 0; fm < 2; ++fm)
#pragma unroll
        for (int fn = 0; fn < 2; ++fn)
#pragma unroll
            for (int q = 0; q < 4; ++q)
#pragma unroll
                for (int j = 0; j < 4; ++j) {
                    int row = brow + wy * 64 + fm * 32 + q * 8 + hi * 4 + j;
                    int col = bcol + wx * 64 + fn * 32 + fl;
                    __builtin_nontemporal_store(acc[fm][fn][q * 4 + j],
                                                &out[(size_t)row * N + col]);
                }
}

extern "C" void kernel_launch(void* const* d_in, const int* in_sizes, int n_in,
                              void* d_out, int out_size, void* d_ws, size_t ws_size,
                              hipStream_t stream) {
    const float* x   = (const float*)d_in[0];
    const float* w   = (const float*)d_in[1];
    const float* wsi = (const float*)d_in[2];
    float* out = (float*)d_out;

    const int K = 4096;
    const int M = in_sizes[0] / K;       // 4096
    const int N = in_sizes[1] / K;       // 16384

    uint8_t* xq  = (uint8_t*)d_ws;                      // M*K bytes
    uint8_t* wq  = xq + (size_t)M * K;                  // N*K bytes
    float*   sxT = (float*)(wq + (size_t)N * K);        // (K/128)*M floats

    int waves = M * (K / BSQ);
    act_quant_kernel<<<dim3(waves / 4), dim3(256), 0, stream>>>(x, xq, sxT, M, K);

    size_t wn = (size_t)N * K;
    weight_quant_kernel<<<dim3((unsigned)(wn / 4 / 256)), dim3(256), 0, stream>>>(w, wq, wn);

    dim3 grid(N / TN, M / TM);
    fp8_gemm_mx<<<grid, dim3(256), 0, stream>>>(xq, wq, sxT, wsi, out, M, N, K);
}